// Round 14
// baseline (202.558 us; speedup 1.0000x reference)
//
#include <hip/hip_runtime.h>
#include <cmath>

typedef short bf16x8 __attribute__((ext_vector_type(8)));
typedef float f32x4 __attribute__((ext_vector_type(4)));

struct Coeffs { float k[11]; };

__device__ __forceinline__ ushort f2bf(float f) {          // RNE bf16 (finite inputs)
    unsigned u = __float_as_uint(f);
    u += 0x7fff + ((u >> 16) & 1);
    return (ushort)(u >> 16);
}

__device__ __forceinline__ unsigned pk2(float lo, float hi) {  // packed bf16 pair
    unsigned d;
    asm("v_cvt_pk_bf16_f32 %0, %1, %2" : "=v"(d) : "v"(lo), "v"(hi));
    return d;
}

__device__ __forceinline__ float frcp(float x) { return __builtin_amdgcn_rcpf(x); }

__device__ __forceinline__ float4 ld4s(const float* __restrict__ p, int r, int c, int H, int W) {
    float4 v = make_float4(0.f, 0.f, 0.f, 0.f);
    if (r >= 0 && r < H) {
        const float* row = p + (size_t)r * W;
        if (c >= 0 && c + 3 < W) {
            v = *reinterpret_cast<const float4*>(row + c);
        } else {
            if (c + 0 >= 0 && c + 0 < W) v.x = row[c + 0];
            if (c + 1 >= 0 && c + 1 < W) v.y = row[c + 1];
            if (c + 2 >= 0 && c + 2 < W) v.z = row[c + 2];
            if (c + 3 >= 0 && c + 3 < W) v.w = row[c + 3];
        }
    }
    return v;
}

union FragU { ushort us[8]; bf16x8 v; uint4 q; };
union RdU   { uint4 q; bf16x8 v; };

// ============ init: build banded MFMA fragments once into d_ws =====================
__global__ __launch_bounds__(64)
void init_frag_kernel(uint4* __restrict__ tab, Coeffs cf) {
    const int lane = threadIdx.x;
    const int lj   = lane & 15;
    const int part = lane >> 4;
    FragU bHf, aVf;
    #pragma unroll
    for (int i = 0; i < 8; ++i) {
        const int kk = part * 8 + i;
        const int tH = kk - lj - 3;     // B_H[kk][j] = k[kk-j-3]
        const int tV = kk - lj;         // A_V[j][kk] = k[kk-j]
        float vH = 0.f, vV = 0.f;
        #pragma unroll
        for (int tt = 0; tt < 11; ++tt) {
            vH = (tH == tt) ? cf.k[tt] : vH;
            vV = (tV == tt) ? cf.k[tt] : vV;
        }
        bHf.us[i] = f2bf(vH);
        aVf.us[i] = f2bf(vV);
    }
    tab[lane]      = bHf.q;
    tab[64 + lane] = aVf.q;
}

// ---------------- level-0 helpers ---------------------------------------------------
__device__ __forceinline__ void stage_load(const float* __restrict__ p1,
                                           const float* __restrict__ p2,
                                           int H, int W, int gr, int gc0,
                                           float (&a)[12], float (&b)[12]) {
    if (gr >= 0 && gr < H && gc0 >= 0 && gc0 + 12 <= W) {
        const size_t idx = (size_t)gr * W + gc0;
        #pragma unroll
        for (int g = 0; g < 3; ++g) {
            float4 va = *reinterpret_cast<const float4*>(p1 + idx + 4 * g);
            float4 vb = *reinterpret_cast<const float4*>(p2 + idx + 4 * g);
            a[4*g+0]=va.x; a[4*g+1]=va.y; a[4*g+2]=va.z; a[4*g+3]=va.w;
            b[4*g+0]=vb.x; b[4*g+1]=vb.y; b[4*g+2]=vb.z; b[4*g+3]=vb.w;
        }
    } else {
        #pragma unroll
        for (int g = 0; g < 3; ++g) {
            float4 va = ld4s(p1, gr, gc0 + 4 * g, H, W);
            float4 vb = ld4s(p2, gr, gc0 + 4 * g, H, W);
            a[4*g+0]=va.x; a[4*g+1]=va.y; a[4*g+2]=va.z; a[4*g+3]=va.w;
            b[4*g+0]=vb.x; b[4*g+1]=vb.y; b[4*g+2]=vb.z; b[4*g+3]=vb.w;
        }
    }
}

__device__ __forceinline__ void stage_write(const float (&a)[12], const float (&b)[12],
                                            char* q0, char* q1, char* q2) {
    unsigned pks[2][6];
    #pragma unroll
    for (int e = 0; e < 6; ++e) {
        pks[0][e] = pk2(a[2*e], a[2*e+1]);
        pks[1][e] = pk2(b[2*e], b[2*e+1]);
    }
    #pragma unroll
    for (int s = 0; s < 2; ++s) {
        *(uint2*)(q0 + s * 6144) = make_uint2(pks[s][0], pks[s][1]);
        *(uint2*)(q1 + s * 6144) = make_uint2(pks[s][2], pks[s][3]);
        *(uint2*)(q2 + s * 6144) = make_uint2(pks[s][4], pks[s][5]);
    }
}

__device__ __forceinline__ void h_phase(const char* a0p, const char* a1p, char* st,
                                        const bf16x8 bH, const f32x4 zf) {
    #pragma unroll
    for (int cg = 0; cg < 2; ++cg) {
        const char* ap = cg ? a1p : a0p;
        uint4 da = *(const uint4*)(ap);           // stream a
        uint4 db = *(const uint4*)(ap + 6144);    // stream b
        unsigned wa[4] = {da.x, da.y, da.z, da.w};
        unsigned wb[4] = {db.x, db.y, db.z, db.w};
        uint4 qaa, qbb, qab;
        unsigned* paa = &qaa.x; unsigned* pbb = &qbb.x; unsigned* pab = &qab.x;
        #pragma unroll
        for (int e = 0; e < 4; ++e) {
            const float alo = __uint_as_float(wa[e] << 16);
            const float ahi = __uint_as_float(wa[e] & 0xffff0000u);
            const float blo = __uint_as_float(wb[e] << 16);
            const float bhi = __uint_as_float(wb[e] & 0xffff0000u);
            paa[e] = pk2(alo * alo, ahi * ahi);
            pbb[e] = pk2(blo * blo, bhi * bhi);
            pab[e] = pk2(alo * blo, ahi * bhi);
        }
        RdU f0, f1, f2, f3, f4;
        f0.q = da; f1.q = db; f2.q = qaa; f3.q = qbb; f4.q = qab;
        f32x4 d0 = __builtin_amdgcn_mfma_f32_16x16x32_bf16(f0.v, bH, zf, 0, 0, 0);
        f32x4 d1 = __builtin_amdgcn_mfma_f32_16x16x32_bf16(f1.v, bH, zf, 0, 0, 0);
        f32x4 d2 = __builtin_amdgcn_mfma_f32_16x16x32_bf16(f2.v, bH, zf, 0, 0, 0);
        f32x4 d3 = __builtin_amdgcn_mfma_f32_16x16x32_bf16(f3.v, bH, zf, 0, 0, 0);
        f32x4 d4 = __builtin_amdgcn_mfma_f32_16x16x32_bf16(f4.v, bH, zf, 0, 0, 0);
        char* sc = st + cg * 2048;
        *(uint2*)(sc)          = make_uint2(pk2(d0[0], d0[1]), pk2(d0[2], d0[3]));
        *(uint2*)(sc + 4096)   = make_uint2(pk2(d1[0], d1[1]), pk2(d1[2], d1[3]));
        *(uint2*)(sc + 8192)   = make_uint2(pk2(d2[0], d2[1]), pk2(d2[2], d2[3]));
        *(uint2*)(sc + 12288)  = make_uint2(pk2(d3[0], d3[1]), pk2(d3[2], d3[3]));
        *(uint2*)(sc + 16384)  = make_uint2(pk2(d4[0], d4[1]), pk2(d4[2], d4[3]));
    }
}

__device__ __forceinline__ void v_phase(const char* hb, const bf16x8 aV, const f32x4 zf,
                                        float& ssim_acc, float& cs_acc) {
    f32x4 acc[5];
    #pragma unroll
    for (int s = 0; s < 5; ++s) {
        RdU br;
        br.q = *(const uint4*)(hb + s * 4096);
        acc[s] = __builtin_amdgcn_mfma_f32_16x16x32_bf16(aV, br.v, zf, 0, 0, 0);
    }
    const float C1 = 1e-4f, C2 = 9e-4f;
    #pragma unroll
    for (int r = 0; r < 4; ++r) {
        const float mu1 = acc[0][r], mu2 = acc[1][r];
        const float m11 = acc[2][r], m22 = acc[3][r], m12 = acc[4][r];
        const float mu1s = mu1 * mu1, mu2s = mu2 * mu2, mu12 = mu1 * mu2;
        const float v1 = 2.f * (m12 - mu12) + C2;
        const float v2 = (m11 - mu1s) + (m22 - mu2s) + C2;
        const float r2 = frcp(v2);
        const float rd = frcp(mu1s + mu2s + C1);
        cs_acc   += v1 * r2;
        ssim_acc += (2.f * mu12 + C1) * v1 * r2 * rd;
    }
}

__device__ __forceinline__ void pool_load8(const float* __restrict__ p1,
                                           const float* __restrict__ p2,
                                           size_t idx, int W, float4 (&P)[8]) {
    P[0] = *reinterpret_cast<const float4*>(p1 + idx);
    P[1] = *reinterpret_cast<const float4*>(p1 + idx + 4);
    P[2] = *reinterpret_cast<const float4*>(p1 + idx + W);
    P[3] = *reinterpret_cast<const float4*>(p1 + idx + W + 4);
    P[4] = *reinterpret_cast<const float4*>(p2 + idx);
    P[5] = *reinterpret_cast<const float4*>(p2 + idx + 4);
    P[6] = *reinterpret_cast<const float4*>(p2 + idx + W);
    P[7] = *reinterpret_cast<const float4*>(p2 + idx + W + 4);
}

__device__ __forceinline__ void pool_store8(const float4 (&P)[8],
                                            float* __restrict__ o1, float* __restrict__ o2,
                                            int bc, int H, int W, int r0, int c0t,
                                            int i, int h) {
    float4 oa, ob;
    oa.x = 0.25f*(P[0].x+P[0].y+P[2].x+P[2].y); oa.y = 0.25f*(P[0].z+P[0].w+P[2].z+P[2].w);
    oa.z = 0.25f*(P[1].x+P[1].y+P[3].x+P[3].y); oa.w = 0.25f*(P[1].z+P[1].w+P[3].z+P[3].w);
    ob.x = 0.25f*(P[4].x+P[4].y+P[6].x+P[6].y); ob.y = 0.25f*(P[4].z+P[4].w+P[6].z+P[6].w);
    ob.z = 0.25f*(P[5].x+P[5].y+P[7].x+P[7].y); ob.w = 0.25f*(P[5].z+P[5].w+P[7].z+P[7].w);
    const int W2 = W >> 1;
    const size_t base = (size_t)bc * (size_t)(H >> 1) * W2
                      + (size_t)(r0/2 + i) * W2 + (c0t/2 + 4*h);
    *reinterpret_cast<float4*>(o1 + base) = oa;
    *reinterpret_cast<float4*>(o2 + base) = ob;
}

// ============ Level 0: 4-tile rolling-prefetch MFMA kernel =========================
// grid (W/128, H/32, B*C). Tiles at c0, c0+32, c0+64, c0+96.
__global__ __launch_bounds__(256)
void ssim_level0_mfma(const float* __restrict__ i1, const float* __restrict__ i2,
                      float* __restrict__ o1, float* __restrict__ o2,
                      int H, int W,
                      double* __restrict__ accum,
                      const uint4* __restrict__ frag_tab)
{
    __shared__ __align__(16) ushort A_lds[2][48][64];   // 12.3 KB (a,b only)
    __shared__ __align__(16) ushort H_T [5][32][64];    // 20.5 KB
    __shared__ double red[2][4];

    const int tid  = threadIdx.x;
    const int lane = tid & 63;
    const int lj   = lane & 15;
    const int part = lane >> 4;
    const int swz  = (lane & 7) << 4;
    const int wv   = __builtin_amdgcn_readfirstlane(tid) >> 6;

    const int bc = blockIdx.z;
    const int r0 = blockIdx.y * 32;
    const int c0 = blockIdx.x * 128;
    const float* p1 = i1 + (size_t)bc * H * W;
    const float* p2 = i2 + (size_t)bc * H * W;

    RdU bHu, aVu;
    bHu.q = frag_tab[lane];
    aVu.q = frag_tab[64 + lane];
    const bf16x8 bH = bHu.v;
    const bf16x8 aV = aVu.v;
    const f32x4 zf = {0.f, 0.f, 0.f, 0.f};

    float ssim_acc = 0.f, cs_acc = 0.f;

    const bool stager = (tid < 192);
    const bool pooler = !stager && (o1 != nullptr);

    // stager geometry
    const int row_rel = tid >> 2;     // 0..47 (stagers)
    const int colg    = tid & 3;
    const int grS  = r0 - 5 + row_rel;
    const int gcA  = c0 - 8 + 12 * colg;
    char *q0 = nullptr, *q1 = nullptr, *q2 = nullptr;
    {
        const int cb   = 24 * colg;
        const int swzr = (row_rel & 7) << 4;
        char* base0 = (char*)&A_lds[0][0][0] + row_rel * 128;
        q0 = base0 + ((cb)      ^ swzr);
        q1 = base0 + ((cb + 8)  ^ swzr);
        q2 = base0 + ((cb + 16) ^ swzr);
    }

    // pool geometry
    const int pi = (tid - 192) & 15;
    const int ph = (tid - 192) >> 4;
    const size_t pIdxA = (size_t)(r0 + 2 * pi) * W + (c0 + 8 * ph);

    // phase addresses (loop-invariant)
    const char* Ab  = (const char*)&A_lds[0][0][0] + wv * 2048 + lj * 128;
    const char* a0p = Ab + ((part * 16)      ^ swz);
    const char* a1p = Ab + ((32 + part * 16) ^ swz);
    char* st = (char*)&H_T[0][0][0] + lj * 128 + ((wv * 32 + part * 8) ^ swz);
    const int rg2 = wv >> 1, cg2 = wv & 1;
    const char* hb = (const char*)&H_T[0][0][0] + cg2 * 2048 + lj * 128
                   + ((rg2 * 32 + part * 16) ^ swz);

    // register slots (named, statically indexed)
    float aX[12], bX[12], aY[12], bY[12];
    float4 PX[8], PY[8];

    // ---- Step 1: load A(->X) + B(->Y); write A. Pool: A fully. ----
    if (stager) {
        stage_load(p1, p2, H, W, grS, gcA,      aX, bX);
        stage_load(p1, p2, H, W, grS, gcA + 32, aY, bY);
        stage_write(aX, bX, q0, q1, q2);
    } else if (pooler) {
        pool_load8(p1, p2, pIdxA, W, PX);
        pool_store8(PX, o1, o2, bc, H, W, r0, c0, pi, ph);
    }
    __syncthreads();

    // ---- H(A) ----
    if (wv < 3) h_phase(a0p, a1p, st, bH, zf);
    __syncthreads();

    // ---- Step 3: issue C(->X); write B(Y). Pool: issue B(->PX). V(A). ----
    if (stager) {
        stage_load(p1, p2, H, W, grS, gcA + 64, aX, bX);
        stage_write(aY, bY, q0, q1, q2);
    } else if (pooler) {
        pool_load8(p1, p2, pIdxA + 32, W, PX);
    }
    v_phase(hb, aV, zf, ssim_acc, cs_acc);
    __syncthreads();

    // ---- H(B) ----
    if (wv < 3) h_phase(a0p, a1p, st, bH, zf);
    __syncthreads();

    // ---- Step 5: issue D(->Y); write C(X). Pool: store B, issue C(->PY). V(B). ----
    if (stager) {
        stage_load(p1, p2, H, W, grS, gcA + 96, aY, bY);
        stage_write(aX, bX, q0, q1, q2);
    } else if (pooler) {
        pool_store8(PX, o1, o2, bc, H, W, r0, c0 + 32, pi, ph);
        pool_load8(p1, p2, pIdxA + 64, W, PY);
    }
    v_phase(hb, aV, zf, ssim_acc, cs_acc);
    __syncthreads();

    // ---- H(C) ----
    if (wv < 3) h_phase(a0p, a1p, st, bH, zf);
    __syncthreads();

    // ---- Step 7: write D(Y). Pool: store C, issue D(->PX). V(C). ----
    if (stager) {
        stage_write(aY, bY, q0, q1, q2);
    } else if (pooler) {
        pool_store8(PY, o1, o2, bc, H, W, r0, c0 + 64, pi, ph);
        pool_load8(p1, p2, pIdxA + 96, W, PX);
    }
    v_phase(hb, aV, zf, ssim_acc, cs_acc);
    __syncthreads();

    // ---- H(D) ----
    if (wv < 3) h_phase(a0p, a1p, st, bH, zf);
    __syncthreads();

    // ---- Step 9: Pool: store D. V(D). ----
    if (pooler) {
        pool_store8(PX, o1, o2, bc, H, W, r0, c0 + 96, pi, ph);
    }
    v_phase(hb, aV, zf, ssim_acc, cs_acc);

    // ---- single reduction + atomic for all four tiles ----
    #pragma unroll
    for (int off = 32; off > 0; off >>= 1) {
        ssim_acc += __shfl_down(ssim_acc, off);
        cs_acc   += __shfl_down(cs_acc, off);
    }
    if (lane == 0) { red[0][wv] = (double)ssim_acc; red[1][wv] = (double)cs_acc; }
    __syncthreads();
    if (tid == 0) {
        double s = red[0][0] + red[0][1] + red[0][2] + red[0][3];
        double c = red[1][0] + red[1][1] + red[1][2] + red[1][3];
        int slot = (blockIdx.x + blockIdx.y * 3 + blockIdx.z * 7) & 63;
        atomicAdd(&accum[slot], s);
        atomicAdd(&accum[64 + slot], c);
    }
}

// ============ Level 1: direct-global MFMA kernel (R8 structure, proven) ============
__global__ __launch_bounds__(256)
void ssim_level1_mfma(const float* __restrict__ i1, const float* __restrict__ i2,
                      float* __restrict__ o1, float* __restrict__ o2,
                      int H, int W,
                      double* __restrict__ accum,
                      const uint4* __restrict__ frag_tab)
{
    __shared__ __align__(16) ushort H_T[5][32][64];   // 20.5 KB
    __shared__ double red[2][4];

    const int tid  = threadIdx.x;
    const int lane = tid & 63;
    const int lj   = lane & 15;
    const int part = lane >> 4;
    const int swz  = (lane & 7) << 4;
    const int wv   = __builtin_amdgcn_readfirstlane(tid) >> 6;

    const int bc = blockIdx.z;
    const int r0 = blockIdx.y * 32;
    const int c0 = blockIdx.x * 32;
    const float* p1 = i1 + (size_t)bc * H * W;
    const float* p2 = i2 + (size_t)bc * H * W;

    RdU bHu, aVu;
    bHu.q = frag_tab[lane];
    aVu.q = frag_tab[64 + lane];
    const bf16x8 bH = bHu.v;
    const bf16x8 aV = aVu.v;

    const f32x4 zf = {0.f, 0.f, 0.f, 0.f};

    if (wv < 3) {
        const int gr = r0 - 5 + wv * 16 + lj;
        char* st = (char*)&H_T[0][0][0] + lj * 128 + ((wv * 32 + part * 8) ^ swz);
        #pragma unroll
        for (int cg = 0; cg < 2; ++cg) {
            const int gc = c0 - 8 + cg * 16 + part * 8;
            float a8[8], b8[8];
            if (gr >= 0 && gr < H && gc >= 0 && gc + 8 <= W) {
                const size_t idx = (size_t)gr * W + gc;
                float4 va0 = *reinterpret_cast<const float4*>(p1 + idx);
                float4 va1 = *reinterpret_cast<const float4*>(p1 + idx + 4);
                float4 vb0 = *reinterpret_cast<const float4*>(p2 + idx);
                float4 vb1 = *reinterpret_cast<const float4*>(p2 + idx + 4);
                a8[0]=va0.x; a8[1]=va0.y; a8[2]=va0.z; a8[3]=va0.w;
                a8[4]=va1.x; a8[5]=va1.y; a8[6]=va1.z; a8[7]=va1.w;
                b8[0]=vb0.x; b8[1]=vb0.y; b8[2]=vb0.z; b8[3]=vb0.w;
                b8[4]=vb1.x; b8[5]=vb1.y; b8[6]=vb1.z; b8[7]=vb1.w;
            } else {
                float4 va0 = ld4s(p1, gr, gc, H, W);
                float4 va1 = ld4s(p1, gr, gc + 4, H, W);
                float4 vb0 = ld4s(p2, gr, gc, H, W);
                float4 vb1 = ld4s(p2, gr, gc + 4, H, W);
                a8[0]=va0.x; a8[1]=va0.y; a8[2]=va0.z; a8[3]=va0.w;
                a8[4]=va1.x; a8[5]=va1.y; a8[6]=va1.z; a8[7]=va1.w;
                b8[0]=vb0.x; b8[1]=vb0.y; b8[2]=vb0.z; b8[3]=vb0.w;
                b8[4]=vb1.x; b8[5]=vb1.y; b8[6]=vb1.z; b8[7]=vb1.w;
            }

            unsigned pkf[5][4];
            #pragma unroll
            for (int e = 0; e < 4; ++e) {
                const float a0 = a8[2*e], a1 = a8[2*e+1];
                const float b0 = b8[2*e], b1 = b8[2*e+1];
                pkf[0][e] = pk2(a0, a1);
                pkf[1][e] = pk2(b0, b1);
                pkf[2][e] = pk2(a0*a0, a1*a1);
                pkf[3][e] = pk2(b0*b0, b1*b1);
                pkf[4][e] = pk2(a0*b0, a1*b1);
            }
            #pragma unroll
            for (int s = 0; s < 5; ++s) {
                RdU fr;
                fr.q.x = pkf[s][0]; fr.q.y = pkf[s][1];
                fr.q.z = pkf[s][2]; fr.q.w = pkf[s][3];
                f32x4 d = __builtin_amdgcn_mfma_f32_16x16x32_bf16(fr.v, bH, zf, 0, 0, 0);
                *(uint2*)(st + cg * 2048 + s * 4096)
                    = make_uint2(pk2(d[0], d[1]), pk2(d[2], d[3]));
            }
        }
    } else if (o1 != nullptr) {
        const int p = tid - 192;
        const int i = p & 15;
        const int h = p >> 4;
        const size_t idx = (size_t)(r0 + 2 * i) * W + (c0 + 8 * h);
        const float* pa = p1 + idx;
        const float* pb = p2 + idx;
        float4 a00 = *reinterpret_cast<const float4*>(pa);
        float4 a01 = *reinterpret_cast<const float4*>(pa + 4);
        float4 a10 = *reinterpret_cast<const float4*>(pa + W);
        float4 a11 = *reinterpret_cast<const float4*>(pa + W + 4);
        float4 b00 = *reinterpret_cast<const float4*>(pb);
        float4 b01 = *reinterpret_cast<const float4*>(pb + 4);
        float4 b10 = *reinterpret_cast<const float4*>(pb + W);
        float4 b11 = *reinterpret_cast<const float4*>(pb + W + 4);
        float4 oa, ob;
        oa.x = 0.25f*(a00.x+a00.y+a10.x+a10.y); oa.y = 0.25f*(a00.z+a00.w+a10.z+a10.w);
        oa.z = 0.25f*(a01.x+a01.y+a11.x+a11.y); oa.w = 0.25f*(a01.z+a01.w+a11.z+a11.w);
        ob.x = 0.25f*(b00.x+b00.y+b10.x+b10.y); ob.y = 0.25f*(b00.z+b00.w+b10.z+b10.w);
        ob.z = 0.25f*(b01.x+b01.y+b11.x+b11.y); ob.w = 0.25f*(b01.z+b01.w+b11.z+b11.w);
        const int W2 = W >> 1;
        const size_t base = (size_t)bc * (size_t)(H >> 1) * W2
                          + (size_t)(r0/2 + i) * W2 + (c0/2 + 4*h);
        *reinterpret_cast<float4*>(o1 + base) = oa;
        *reinterpret_cast<float4*>(o2 + base) = ob;
    }
    __syncthreads();

    const int rg2 = wv >> 1;
    const int cg2 = wv & 1;
    const char* hb = (const char*)&H_T[0][0][0] + cg2 * 2048 + lj * 128
                   + ((rg2 * 32 + part * 16) ^ swz);
    f32x4 acc[5];
    #pragma unroll
    for (int s = 0; s < 5; ++s) {
        RdU br;
        br.q = *(const uint4*)(hb + s * 4096);
        acc[s] = __builtin_amdgcn_mfma_f32_16x16x32_bf16(aV, br.v, zf, 0, 0, 0);
    }

    const float C1 = 1e-4f, C2 = 9e-4f;
    float ssim_acc = 0.f, cs_acc = 0.f;
    #pragma unroll
    for (int r = 0; r < 4; ++r) {
        const float mu1 = acc[0][r], mu2 = acc[1][r];
        const float m11 = acc[2][r], m22 = acc[3][r], m12 = acc[4][r];
        const float mu1s = mu1 * mu1, mu2s = mu2 * mu2, mu12 = mu1 * mu2;
        const float v1 = 2.f * (m12 - mu12) + C2;
        const float v2 = (m11 - mu1s) + (m22 - mu2s) + C2;
        const float r2 = frcp(v2);
        const float rd = frcp(mu1s + mu2s + C1);
        cs_acc   += v1 * r2;
        ssim_acc += (2.f * mu12 + C1) * v1 * r2 * rd;
    }

    #pragma unroll
    for (int off = 32; off > 0; off >>= 1) {
        ssim_acc += __shfl_down(ssim_acc, off);
        cs_acc   += __shfl_down(cs_acc, off);
    }
    if (lane == 0) { red[0][wv] = (double)ssim_acc; red[1][wv] = (double)cs_acc; }
    __syncthreads();
    if (tid == 0) {
        double s = red[0][0] + red[0][1] + red[0][2] + red[0][3];
        double c = red[1][0] + red[1][1] + red[1][2] + red[1][3];
        int slot = (blockIdx.x + blockIdx.y * 3 + blockIdx.z * 7) & 63;
        atomicAdd(&accum[slot], s);
        atomicAdd(&accum[64 + slot], c);
    }
}

// =================== f32 kernel (proven): levels 2-4 ===============================
#define SPF 33
#define HRF 42

__global__ __launch_bounds__(256)
void ssim_level_f32(const float* __restrict__ i1, const float* __restrict__ i2,
                    float* __restrict__ o1, float* __restrict__ o2,
                    int H, int W,
                    double* __restrict__ accum, Coeffs cf)
{
    __shared__ __align__(16) float varr[5][HRF][SPF];
    __shared__ __align__(16) float phl[2][16][16];
    __shared__ double red[2][4];

    const int tid = threadIdx.x;
    const int bc  = blockIdx.z;
    const int r0 = blockIdx.y * 32;
    const int c0 = blockIdx.x * 32;
    const float* p1 = i1 + (size_t)bc * H * W;
    const float* p2 = i2 + (size_t)bc * H * W;

    const int row_rel = tid >> 2;
    const int j  = tid & 3;
    const int cl = 8 * j;
    float hpA[4], hpB[4];
    bool pool_thread = false;

    if (tid < HRF * 4) {
        const int gr  = r0 + row_rel - 5;
        const int gcb = c0 + cl - 8;

        float a[24], b[24];
        if (gr >= 0 && gr < H && gcb >= 0 && gcb + 24 <= W) {
            const size_t idx = (size_t)gr * W + gcb;
            const float* pa = p1 + idx;
            const float* pb = p2 + idx;
            #pragma unroll
            for (int g = 0; g < 6; ++g) {
                float4 va = *reinterpret_cast<const float4*>(pa + 4 * g);
                float4 vb = *reinterpret_cast<const float4*>(pb + 4 * g);
                a[4*g+0]=va.x; a[4*g+1]=va.y; a[4*g+2]=va.z; a[4*g+3]=va.w;
                b[4*g+0]=vb.x; b[4*g+1]=vb.y; b[4*g+2]=vb.z; b[4*g+3]=vb.w;
            }
        } else {
            #pragma unroll
            for (int g = 0; g < 6; ++g) {
                float4 va = ld4s(p1, gr, gcb + 4 * g, H, W);
                float4 vb = ld4s(p2, gr, gcb + 4 * g, H, W);
                a[4*g+0]=va.x; a[4*g+1]=va.y; a[4*g+2]=va.z; a[4*g+3]=va.w;
                b[4*g+0]=vb.x; b[4*g+1]=vb.y; b[4*g+2]=vb.z; b[4*g+3]=vb.w;
            }
        }

        float acc[5][8] = {};
        #pragma unroll
        for (int i = 0; i < 24; ++i) {
            float av = a[i], bv = b[i];
            float pa2 = av * av, pb2 = bv * bv, pab = av * bv;
            #pragma unroll
            for (int jo = 0; jo < 8; ++jo) {
                const int t = i - 3 - jo;
                if (t >= 0 && t <= 10) {
                    const float kk = cf.k[t];
                    acc[0][jo] += kk * av;  acc[1][jo] += kk * bv;
                    acc[2][jo] += kk * pa2; acc[3][jo] += kk * pb2;
                    acc[4][jo] += kk * pab;
                }
            }
        }
        #pragma unroll
        for (int s = 0; s < 5; ++s) {
            *reinterpret_cast<float4*>(&varr[s][row_rel][cl]) =
                make_float4(acc[s][0], acc[s][1], acc[s][2], acc[s][3]);
            *reinterpret_cast<float4*>(&varr[s][row_rel][cl + 4]) =
                make_float4(acc[s][4], acc[s][5], acc[s][6], acc[s][7]);
        }

        if (o1 != nullptr && row_rel >= 5 && row_rel <= 36) {
            #pragma unroll
            for (int p = 0; p < 4; ++p) {
                hpA[p] = a[8 + 2*p] + a[9 + 2*p];
                hpB[p] = b[8 + 2*p] + b[9 + 2*p];
            }
            if (row_rel & 1) {
                const int i = (row_rel - 5) >> 1;
                *reinterpret_cast<float4*>(&phl[0][i][4*j]) = make_float4(hpA[0],hpA[1],hpA[2],hpA[3]);
                *reinterpret_cast<float4*>(&phl[1][i][4*j]) = make_float4(hpB[0],hpB[1],hpB[2],hpB[3]);
            } else if (row_rel >= 6) {
                pool_thread = true;
            }
        }
    }
    __syncthreads();

    if (pool_thread) {
        const int i = (row_rel - 6) >> 1;
        const int W2 = W >> 1;
        float4 qa = *reinterpret_cast<const float4*>(&phl[0][i][4*j]);
        float4 qb = *reinterpret_cast<const float4*>(&phl[1][i][4*j]);
        qa.x = 0.25f*(qa.x + hpA[0]); qa.y = 0.25f*(qa.y + hpA[1]);
        qa.z = 0.25f*(qa.z + hpA[2]); qa.w = 0.25f*(qa.w + hpA[3]);
        qb.x = 0.25f*(qb.x + hpB[0]); qb.y = 0.25f*(qb.y + hpB[1]);
        qb.z = 0.25f*(qb.z + hpB[2]); qb.w = 0.25f*(qb.w + hpB[3]);
        const size_t base = (size_t)bc * (size_t)(H >> 1) * W2
                          + (size_t)(r0/2 + i) * W2 + (c0/2 + 4*j);
        *reinterpret_cast<float4*>(o1 + base) = qa;
        *reinterpret_cast<float4*>(o2 + base) = qb;
    }

    const int col = tid & 31;
    const int rg  = tid >> 5;

    float acc[5][4] = {};
    #pragma unroll
    for (int t = 0; t < 14; ++t) {
        const int m = rg * 4 + t;
        #pragma unroll
        for (int s = 0; s < 5; ++s) {
            const float val = varr[s][m][col];
            #pragma unroll
            for (int i = 0; i < 4; ++i) {
                const int tap = t - i;
                if (tap >= 0 && tap <= 10) acc[s][i] += cf.k[tap] * val;
            }
        }
    }

    const float C1 = 1e-4f, C2 = 9e-4f;
    float ssim_acc = 0.f, cs_acc = 0.f;
    #pragma unroll
    for (int i = 0; i < 4; ++i) {
        const float mu1 = acc[0][i], mu2 = acc[1][i];
        const float m11 = acc[2][i], m22 = acc[3][i], m12 = acc[4][i];
        const float mu1s = mu1 * mu1, mu2s = mu2 * mu2, mu12 = mu1 * mu2;
        const float v1 = 2.f * (m12 - mu12) + C2;
        const float v2 = (m11 - mu1s) + (m22 - mu2s) + C2;
        const float r2 = frcp(v2);
        const float rd = frcp(mu1s + mu2s + C1);
        cs_acc   += v1 * r2;
        ssim_acc += (2.f * mu12 + C1) * v1 * r2 * rd;
    }

    #pragma unroll
    for (int off = 32; off > 0; off >>= 1) {
        ssim_acc += __shfl_down(ssim_acc, off);
        cs_acc   += __shfl_down(cs_acc, off);
    }
    const int wave = tid >> 6, lane = tid & 63;
    if (lane == 0) { red[0][wave] = (double)ssim_acc; red[1][wave] = (double)cs_acc; }
    __syncthreads();
    if (tid == 0) {
        double s = red[0][0] + red[0][1] + red[0][2] + red[0][3];
        double c = red[1][0] + red[1][1] + red[1][2] + red[1][3];
        int slot = (blockIdx.x + blockIdx.y * 3 + blockIdx.z * 7) & 63;
        atomicAdd(&accum[slot], s);
        atomicAdd(&accum[64 + slot], c);
    }
}

__global__ __launch_bounds__(64)
void finalize_kernel(const double* __restrict__ accum,  // [5][2][64]
                     float* __restrict__ out, int BC)
{
    __shared__ double sums[5][2];
    int tid = threadIdx.x;
    for (int lvl = 0; lvl < 5; ++lvl) {
        for (int m = 0; m < 2; ++m) {
            double v = accum[(lvl * 2 + m) * 64 + tid];
            for (int off = 32; off > 0; off >>= 1) v += __shfl_down(v, off);
            if (tid == 0) sums[lvl][m] = v;
        }
    }
    __syncthreads();
    if (tid == 0) {
        const double w[5] = {0.0448, 0.2856, 0.3001, 0.2363, 0.1333};
        double prod = 1.0;
        for (int lvl = 0; lvl < 5; ++lvl) {
            int hw = (512 >> lvl);
            double cnt = (double)BC * (double)hw * (double)hw;
            double mssim = sums[lvl][0] / cnt;
            double mcs   = sums[lvl][1] / cnt;
            if (lvl < 4) {
                prod *= pow(mcs, w[lvl]);
            } else {
                double p2 = pow(mssim, w[4]);
                prod *= p2 * p2 * p2 * p2;
            }
        }
        out[0] = (float)(1.0 - prod);
    }
}

extern "C" void kernel_launch(void* const* d_in, const int* in_sizes, int n_in,
                              void* d_out, int out_size, void* d_ws, size_t ws_size,
                              hipStream_t stream) {
    const float* img1 = (const float*)d_in[0];
    const float* img2 = (const float*)d_in[1];
    float* out = (float*)d_out;
    char* ws = (char*)d_ws;

    const int BC = in_sizes[0] / (512 * 512);   // 96

    // ws layout: [0,5120) accum double[5][2][64]; [6144,8192) frag table;
    // pyramid from 8192
    double* accum = (double*)ws;
    uint4*  ftab  = (uint4*)(ws + 6144);
    size_t off = 8192;
    float* lvl1[5] = {nullptr, nullptr, nullptr, nullptr, nullptr};
    float* lvl2[5] = {nullptr, nullptr, nullptr, nullptr, nullptr};
    for (int l = 1; l < 5; ++l) {
        size_t hw = (size_t)(512 >> l) * (512 >> l);
        lvl1[l] = (float*)(ws + off); off += (size_t)BC * hw * sizeof(float);
        lvl2[l] = (float*)(ws + off); off += (size_t)BC * hw * sizeof(float);
    }

    hipMemsetAsync(accum, 0, 5 * 2 * 64 * sizeof(double), stream);

    // Gaussian window, faithful to the reference's POSITIVE exponent bug
    Coeffs cf;
    {
        double kd[11], sum = 0.0;
        for (int i = 0; i < 11; ++i) { kd[i] = exp(((double)((i-5)*(i-5))) / 4.5); sum += kd[i]; }
        for (int i = 0; i < 11; ++i) cf.k[i] = (float)(kd[i] / sum);
    }

    init_frag_kernel<<<1, 64, 0, stream>>>(ftab, cf);

    const float* cur1 = img1;
    const float* cur2 = img2;
    for (int lvl = 0; lvl < 5; ++lvl) {
        int H = 512 >> lvl, W = H;
        float* n1 = (lvl < 4) ? lvl1[lvl + 1] : nullptr;
        float* n2 = (lvl < 4) ? lvl2[lvl + 1] : nullptr;
        if (lvl == 0) {
            dim3 grid(W / 128, H / 32, BC);
            ssim_level0_mfma<<<grid, 256, 0, stream>>>(cur1, cur2, n1, n2, H, W,
                                                       accum + lvl * 128, ftab);
        } else if (lvl == 1) {
            dim3 grid(W / 32, H / 32, BC);
            ssim_level1_mfma<<<grid, 256, 0, stream>>>(cur1, cur2, n1, n2, H, W,
                                                       accum + lvl * 128, ftab);
        } else {
            dim3 grid(W / 32, H / 32, BC);
            ssim_level_f32<<<grid, 256, 0, stream>>>(cur1, cur2, n1, n2, H, W,
                                                     accum + lvl * 128, cf);
        }
        cur1 = n1; cur2 = n2;
    }

    finalize_kernel<<<1, 64, 0, stream>>>(accum, out, BC);
}

// Round 15
// 158.145 us; speedup vs baseline: 1.2808x; 1.2808x over previous
//
#include <hip/hip_runtime.h>
#include <cmath>

typedef short bf16x8 __attribute__((ext_vector_type(8)));
typedef float f32x4 __attribute__((ext_vector_type(4)));

struct Coeffs { float k[11]; };

__device__ __forceinline__ ushort f2bf(float f) {          // RNE bf16 (finite inputs)
    unsigned u = __float_as_uint(f);
    u += 0x7fff + ((u >> 16) & 1);
    return (ushort)(u >> 16);
}

__device__ __forceinline__ unsigned pk2(float lo, float hi) {  // packed bf16 pair
    unsigned d;
    asm("v_cvt_pk_bf16_f32 %0, %1, %2" : "=v"(d) : "v"(lo), "v"(hi));
    return d;
}

__device__ __forceinline__ float frcp(float x) { return __builtin_amdgcn_rcpf(x); }

__device__ __forceinline__ float4 ld4s(const float* __restrict__ p, int r, int c, int H, int W) {
    float4 v = make_float4(0.f, 0.f, 0.f, 0.f);
    if (r >= 0 && r < H) {
        const float* row = p + (size_t)r * W;
        if (c >= 0 && c + 3 < W) {
            v = *reinterpret_cast<const float4*>(row + c);
        } else {
            if (c + 0 >= 0 && c + 0 < W) v.x = row[c + 0];
            if (c + 1 >= 0 && c + 1 < W) v.y = row[c + 1];
            if (c + 2 >= 0 && c + 2 < W) v.z = row[c + 2];
            if (c + 3 >= 0 && c + 3 < W) v.w = row[c + 3];
        }
    }
    return v;
}

union FragU { ushort us[8]; bf16x8 v; uint4 q; };
union RdU   { uint4 q; bf16x8 v; };

// ============ init: build banded MFMA fragments once into d_ws =====================
__global__ __launch_bounds__(64)
void init_frag_kernel(uint4* __restrict__ tab, Coeffs cf) {
    const int lane = threadIdx.x;
    const int lj   = lane & 15;
    const int part = lane >> 4;
    FragU bHf, aVf;
    #pragma unroll
    for (int i = 0; i < 8; ++i) {
        const int kk = part * 8 + i;
        const int tH = kk - lj - 3;     // B_H[kk][j] = k[kk-j-3]
        const int tV = kk - lj;         // A_V[j][kk] = k[kk-j]
        float vH = 0.f, vV = 0.f;
        #pragma unroll
        for (int tt = 0; tt < 11; ++tt) {
            vH = (tH == tt) ? cf.k[tt] : vH;
            vV = (tV == tt) ? cf.k[tt] : vV;
        }
        bHf.us[i] = f2bf(vH);
        aVf.us[i] = f2bf(vV);
    }
    tab[lane]      = bHf.q;
    tab[64 + lane] = aVf.q;
}

// ---------------- MFMA-kernel helpers ----------------------------------------------
__device__ __forceinline__ void stage_load(const float* __restrict__ p1,
                                           const float* __restrict__ p2,
                                           int H, int W, int gr, int gc0,
                                           float (&a)[12], float (&b)[12]) {
    if (gr >= 0 && gr < H && gc0 >= 0 && gc0 + 12 <= W) {
        const size_t idx = (size_t)gr * W + gc0;
        #pragma unroll
        for (int g = 0; g < 3; ++g) {
            float4 va = *reinterpret_cast<const float4*>(p1 + idx + 4 * g);
            float4 vb = *reinterpret_cast<const float4*>(p2 + idx + 4 * g);
            a[4*g+0]=va.x; a[4*g+1]=va.y; a[4*g+2]=va.z; a[4*g+3]=va.w;
            b[4*g+0]=vb.x; b[4*g+1]=vb.y; b[4*g+2]=vb.z; b[4*g+3]=vb.w;
        }
    } else {
        #pragma unroll
        for (int g = 0; g < 3; ++g) {
            float4 va = ld4s(p1, gr, gc0 + 4 * g, H, W);
            float4 vb = ld4s(p2, gr, gc0 + 4 * g, H, W);
            a[4*g+0]=va.x; a[4*g+1]=va.y; a[4*g+2]=va.z; a[4*g+3]=va.w;
            b[4*g+0]=vb.x; b[4*g+1]=vb.y; b[4*g+2]=vb.z; b[4*g+3]=vb.w;
        }
    }
}

__device__ __forceinline__ void stage_write(const float (&a)[12], const float (&b)[12],
                                            char* q0, char* q1, char* q2) {
    unsigned pks[2][6];
    #pragma unroll
    for (int e = 0; e < 6; ++e) {
        pks[0][e] = pk2(a[2*e], a[2*e+1]);
        pks[1][e] = pk2(b[2*e], b[2*e+1]);
    }
    #pragma unroll
    for (int s = 0; s < 2; ++s) {
        *(uint2*)(q0 + s * 6144) = make_uint2(pks[s][0], pks[s][1]);
        *(uint2*)(q1 + s * 6144) = make_uint2(pks[s][2], pks[s][3]);
        *(uint2*)(q2 + s * 6144) = make_uint2(pks[s][4], pks[s][5]);
    }
}

__device__ __forceinline__ void h_phase(const char* a0p, const char* a1p, char* st,
                                        const bf16x8 bH, const f32x4 zf) {
    #pragma unroll
    for (int cg = 0; cg < 2; ++cg) {
        const char* ap = cg ? a1p : a0p;
        uint4 da = *(const uint4*)(ap);           // stream a
        uint4 db = *(const uint4*)(ap + 6144);    // stream b
        unsigned wa[4] = {da.x, da.y, da.z, da.w};
        unsigned wb[4] = {db.x, db.y, db.z, db.w};
        uint4 qaa, qbb, qab;
        unsigned* paa = &qaa.x; unsigned* pbb = &qbb.x; unsigned* pab = &qab.x;
        #pragma unroll
        for (int e = 0; e < 4; ++e) {
            const float alo = __uint_as_float(wa[e] << 16);
            const float ahi = __uint_as_float(wa[e] & 0xffff0000u);
            const float blo = __uint_as_float(wb[e] << 16);
            const float bhi = __uint_as_float(wb[e] & 0xffff0000u);
            paa[e] = pk2(alo * alo, ahi * ahi);
            pbb[e] = pk2(blo * blo, bhi * bhi);
            pab[e] = pk2(alo * blo, ahi * bhi);
        }
        RdU f0, f1, f2, f3, f4;
        f0.q = da; f1.q = db; f2.q = qaa; f3.q = qbb; f4.q = qab;
        f32x4 d0 = __builtin_amdgcn_mfma_f32_16x16x32_bf16(f0.v, bH, zf, 0, 0, 0);
        f32x4 d1 = __builtin_amdgcn_mfma_f32_16x16x32_bf16(f1.v, bH, zf, 0, 0, 0);
        f32x4 d2 = __builtin_amdgcn_mfma_f32_16x16x32_bf16(f2.v, bH, zf, 0, 0, 0);
        f32x4 d3 = __builtin_amdgcn_mfma_f32_16x16x32_bf16(f3.v, bH, zf, 0, 0, 0);
        f32x4 d4 = __builtin_amdgcn_mfma_f32_16x16x32_bf16(f4.v, bH, zf, 0, 0, 0);
        char* sc = st + cg * 2048;
        *(uint2*)(sc)          = make_uint2(pk2(d0[0], d0[1]), pk2(d0[2], d0[3]));
        *(uint2*)(sc + 4096)   = make_uint2(pk2(d1[0], d1[1]), pk2(d1[2], d1[3]));
        *(uint2*)(sc + 8192)   = make_uint2(pk2(d2[0], d2[1]), pk2(d2[2], d2[3]));
        *(uint2*)(sc + 12288)  = make_uint2(pk2(d3[0], d3[1]), pk2(d3[2], d3[3]));
        *(uint2*)(sc + 16384)  = make_uint2(pk2(d4[0], d4[1]), pk2(d4[2], d4[3]));
    }
}

__device__ __forceinline__ void v_phase(const char* hb, const bf16x8 aV, const f32x4 zf,
                                        float& ssim_acc, float& cs_acc) {
    f32x4 acc[5];
    #pragma unroll
    for (int s = 0; s < 5; ++s) {
        RdU br;
        br.q = *(const uint4*)(hb + s * 4096);
        acc[s] = __builtin_amdgcn_mfma_f32_16x16x32_bf16(aV, br.v, zf, 0, 0, 0);
    }
    const float C1 = 1e-4f, C2 = 9e-4f;
    #pragma unroll
    for (int r = 0; r < 4; ++r) {
        const float mu1 = acc[0][r], mu2 = acc[1][r];
        const float m11 = acc[2][r], m22 = acc[3][r], m12 = acc[4][r];
        const float mu1s = mu1 * mu1, mu2s = mu2 * mu2, mu12 = mu1 * mu2;
        const float v1 = 2.f * (m12 - mu12) + C2;
        const float v2 = (m11 - mu1s) + (m22 - mu2s) + C2;
        const float r2 = frcp(v2);
        const float rd = frcp(mu1s + mu2s + C1);
        cs_acc   += v1 * r2;
        ssim_acc += (2.f * mu12 + C1) * v1 * r2 * rd;
    }
}

__device__ __forceinline__ void pool_load8(const float* __restrict__ p1,
                                           const float* __restrict__ p2,
                                           size_t idx, int W, float4 (&P)[8]) {
    P[0] = *reinterpret_cast<const float4*>(p1 + idx);
    P[1] = *reinterpret_cast<const float4*>(p1 + idx + 4);
    P[2] = *reinterpret_cast<const float4*>(p1 + idx + W);
    P[3] = *reinterpret_cast<const float4*>(p1 + idx + W + 4);
    P[4] = *reinterpret_cast<const float4*>(p2 + idx);
    P[5] = *reinterpret_cast<const float4*>(p2 + idx + 4);
    P[6] = *reinterpret_cast<const float4*>(p2 + idx + W);
    P[7] = *reinterpret_cast<const float4*>(p2 + idx + W + 4);
}

__device__ __forceinline__ void pool_store8(const float4 (&P)[8],
                                            float* __restrict__ o1, float* __restrict__ o2,
                                            int bc, int H, int W, int r0, int c0t,
                                            int i, int h) {
    float4 oa, ob;
    oa.x = 0.25f*(P[0].x+P[0].y+P[2].x+P[2].y); oa.y = 0.25f*(P[0].z+P[0].w+P[2].z+P[2].w);
    oa.z = 0.25f*(P[1].x+P[1].y+P[3].x+P[3].y); oa.w = 0.25f*(P[1].z+P[1].w+P[3].z+P[3].w);
    ob.x = 0.25f*(P[4].x+P[4].y+P[6].x+P[6].y); ob.y = 0.25f*(P[4].z+P[4].w+P[6].z+P[6].w);
    ob.z = 0.25f*(P[5].x+P[5].y+P[7].x+P[7].y); ob.w = 0.25f*(P[5].z+P[5].w+P[7].z+P[7].w);
    const int W2 = W >> 1;
    const size_t base = (size_t)bc * (size_t)(H >> 1) * W2
                      + (size_t)(r0/2 + i) * W2 + (c0t/2 + 4*h);
    *reinterpret_cast<float4*>(o1 + base) = oa;
    *reinterpret_cast<float4*>(o2 + base) = ob;
}

// ============ Levels 0-1: 2-tile pipelined, 2-stream A_lds MFMA kernel =============
// grid (W/64, H/32, B*C). Block handles tiles (c0, c0+32) with prefetched registers.
// Proven R13 structure: VGPR~60, 33 KB LDS, ~36% occupancy.
__global__ __launch_bounds__(256)
void ssim_level_mfma2(const float* __restrict__ i1, const float* __restrict__ i2,
                      float* __restrict__ o1, float* __restrict__ o2,
                      int H, int W,
                      double* __restrict__ accum,
                      const uint4* __restrict__ frag_tab)
{
    __shared__ __align__(16) ushort A_lds[2][48][64];   // 12.3 KB (a,b only)
    __shared__ __align__(16) ushort H_T [5][32][64];    // 20.5 KB
    __shared__ double red[2][4];

    const int tid  = threadIdx.x;
    const int lane = tid & 63;
    const int lj   = lane & 15;
    const int part = lane >> 4;
    const int swz  = (lane & 7) << 4;
    const int wv   = __builtin_amdgcn_readfirstlane(tid) >> 6;

    const int bc = blockIdx.z;
    const int r0 = blockIdx.y * 32;
    const int c0 = blockIdx.x * 64;
    const float* p1 = i1 + (size_t)bc * H * W;
    const float* p2 = i2 + (size_t)bc * H * W;

    RdU bHu, aVu;
    bHu.q = frag_tab[lane];
    aVu.q = frag_tab[64 + lane];
    const bf16x8 bH = bHu.v;
    const bf16x8 aV = aVu.v;
    const f32x4 zf = {0.f, 0.f, 0.f, 0.f};

    float ssim_acc = 0.f, cs_acc = 0.f;

    // ---- Step 1: issue ALL global loads (both tiles); write tile A to A_lds ----
    float aB[12], bB[12];                 // tile-B stage, carried across tile A
    char *q0 = nullptr, *q1 = nullptr, *q2 = nullptr;
    if (tid < 192) {
        const int row_rel = tid >> 2;     // 0..47
        const int colg    = tid & 3;
        const int gr  = r0 - 5 + row_rel;
        const int gcA = c0 - 8 + 12 * colg;
        float aA[12], bA[12];
        stage_load(p1, p2, H, W, gr, gcA,      aA, bA);
        stage_load(p1, p2, H, W, gr, gcA + 32, aB, bB);
        const int cb   = 24 * colg;
        const int swzr = (row_rel & 7) << 4;
        char* base0 = (char*)&A_lds[0][0][0] + row_rel * 128;
        q0 = base0 + ((cb)      ^ swzr);
        q1 = base0 + ((cb + 8)  ^ swzr);
        q2 = base0 + ((cb + 16) ^ swzr);
        stage_write(aA, bA, q0, q1, q2);
    } else if (o1 != nullptr) {
        // pool wave: load + pool + store both tiles (f32-exact)
        const int p = tid - 192;
        const int i = p & 15;
        const int h = p >> 4;
        const size_t idxA = (size_t)(r0 + 2 * i) * W + (c0 + 8 * h);
        float4 PA[8], PB[8];
        pool_load8(p1, p2, idxA,      W, PA);
        pool_load8(p1, p2, idxA + 32, W, PB);
        pool_store8(PA, o1, o2, bc, H, W, r0, c0,      i, h);
        pool_store8(PB, o1, o2, bc, H, W, r0, c0 + 32, i, h);
    }
    __syncthreads();

    // loop-invariant phase addresses
    const char* Ab  = (const char*)&A_lds[0][0][0] + wv * 2048 + lj * 128;
    const char* a0p = Ab + ((part * 16)      ^ swz);
    const char* a1p = Ab + ((32 + part * 16) ^ swz);
    char* st = (char*)&H_T[0][0][0] + lj * 128 + ((wv * 32 + part * 8) ^ swz);
    const int rg2 = wv >> 1, cg2 = wv & 1;
    const char* hb = (const char*)&H_T[0][0][0] + cg2 * 2048 + lj * 128
                   + ((rg2 * 32 + part * 16) ^ swz);

    // ---- Step 2: H(A) ----
    if (wv < 3) h_phase(a0p, a1p, st, bH, zf);
    __syncthreads();

    // ---- Step 3: V(A)+SSIM; stagers drop prefetched tile B into A_lds ----
    if (tid < 192) stage_write(aB, bB, q0, q1, q2);
    v_phase(hb, aV, zf, ssim_acc, cs_acc);
    __syncthreads();

    // ---- Step 4: H(B) ----
    if (wv < 3) h_phase(a0p, a1p, st, bH, zf);
    __syncthreads();

    // ---- Step 5: V(B)+SSIM ----
    v_phase(hb, aV, zf, ssim_acc, cs_acc);

    // ---- single reduction + atomic for both tiles ----
    #pragma unroll
    for (int off = 32; off > 0; off >>= 1) {
        ssim_acc += __shfl_down(ssim_acc, off);
        cs_acc   += __shfl_down(cs_acc, off);
    }
    if (lane == 0) { red[0][wv] = (double)ssim_acc; red[1][wv] = (double)cs_acc; }
    __syncthreads();
    if (tid == 0) {
        double s = red[0][0] + red[0][1] + red[0][2] + red[0][3];
        double c = red[1][0] + red[1][1] + red[1][2] + red[1][3];
        int slot = (blockIdx.x + blockIdx.y * 3 + blockIdx.z * 7) & 63;
        atomicAdd(&accum[slot], s);
        atomicAdd(&accum[64 + slot], c);
    }
}

// =================== f32 kernel (proven): levels 2-4 ===============================
#define SPF 33
#define HRF 42

__global__ __launch_bounds__(256)
void ssim_level_f32(const float* __restrict__ i1, const float* __restrict__ i2,
                    float* __restrict__ o1, float* __restrict__ o2,
                    int H, int W,
                    double* __restrict__ accum, Coeffs cf)
{
    __shared__ __align__(16) float varr[5][HRF][SPF];
    __shared__ __align__(16) float phl[2][16][16];
    __shared__ double red[2][4];

    const int tid = threadIdx.x;
    const int bc  = blockIdx.z;
    const int r0 = blockIdx.y * 32;
    const int c0 = blockIdx.x * 32;
    const float* p1 = i1 + (size_t)bc * H * W;
    const float* p2 = i2 + (size_t)bc * H * W;

    const int row_rel = tid >> 2;
    const int j  = tid & 3;
    const int cl = 8 * j;
    float hpA[4], hpB[4];
    bool pool_thread = false;

    if (tid < HRF * 4) {
        const int gr  = r0 + row_rel - 5;
        const int gcb = c0 + cl - 8;

        float a[24], b[24];
        if (gr >= 0 && gr < H && gcb >= 0 && gcb + 24 <= W) {
            const size_t idx = (size_t)gr * W + gcb;
            const float* pa = p1 + idx;
            const float* pb = p2 + idx;
            #pragma unroll
            for (int g = 0; g < 6; ++g) {
                float4 va = *reinterpret_cast<const float4*>(pa + 4 * g);
                float4 vb = *reinterpret_cast<const float4*>(pb + 4 * g);
                a[4*g+0]=va.x; a[4*g+1]=va.y; a[4*g+2]=va.z; a[4*g+3]=va.w;
                b[4*g+0]=vb.x; b[4*g+1]=vb.y; b[4*g+2]=vb.z; b[4*g+3]=vb.w;
            }
        } else {
            #pragma unroll
            for (int g = 0; g < 6; ++g) {
                float4 va = ld4s(p1, gr, gcb + 4 * g, H, W);
                float4 vb = ld4s(p2, gr, gcb + 4 * g, H, W);
                a[4*g+0]=va.x; a[4*g+1]=va.y; a[4*g+2]=va.z; a[4*g+3]=va.w;
                b[4*g+0]=vb.x; b[4*g+1]=vb.y; b[4*g+2]=vb.z; b[4*g+3]=vb.w;
            }
        }

        float acc[5][8] = {};
        #pragma unroll
        for (int i = 0; i < 24; ++i) {
            float av = a[i], bv = b[i];
            float pa2 = av * av, pb2 = bv * bv, pab = av * bv;
            #pragma unroll
            for (int jo = 0; jo < 8; ++jo) {
                const int t = i - 3 - jo;
                if (t >= 0 && t <= 10) {
                    const float kk = cf.k[t];
                    acc[0][jo] += kk * av;  acc[1][jo] += kk * bv;
                    acc[2][jo] += kk * pa2; acc[3][jo] += kk * pb2;
                    acc[4][jo] += kk * pab;
                }
            }
        }
        #pragma unroll
        for (int s = 0; s < 5; ++s) {
            *reinterpret_cast<float4*>(&varr[s][row_rel][cl]) =
                make_float4(acc[s][0], acc[s][1], acc[s][2], acc[s][3]);
            *reinterpret_cast<float4*>(&varr[s][row_rel][cl + 4]) =
                make_float4(acc[s][4], acc[s][5], acc[s][6], acc[s][7]);
        }

        if (o1 != nullptr && row_rel >= 5 && row_rel <= 36) {
            #pragma unroll
            for (int p = 0; p < 4; ++p) {
                hpA[p] = a[8 + 2*p] + a[9 + 2*p];
                hpB[p] = b[8 + 2*p] + b[9 + 2*p];
            }
            if (row_rel & 1) {
                const int i = (row_rel - 5) >> 1;
                *reinterpret_cast<float4*>(&phl[0][i][4*j]) = make_float4(hpA[0],hpA[1],hpA[2],hpA[3]);
                *reinterpret_cast<float4*>(&phl[1][i][4*j]) = make_float4(hpB[0],hpB[1],hpB[2],hpB[3]);
            } else if (row_rel >= 6) {
                pool_thread = true;
            }
        }
    }
    __syncthreads();

    if (pool_thread) {
        const int i = (row_rel - 6) >> 1;
        const int W2 = W >> 1;
        float4 qa = *reinterpret_cast<const float4*>(&phl[0][i][4*j]);
        float4 qb = *reinterpret_cast<const float4*>(&phl[1][i][4*j]);
        qa.x = 0.25f*(qa.x + hpA[0]); qa.y = 0.25f*(qa.y + hpA[1]);
        qa.z = 0.25f*(qa.z + hpA[2]); qa.w = 0.25f*(qa.w + hpA[3]);
        qb.x = 0.25f*(qb.x + hpB[0]); qb.y = 0.25f*(qb.y + hpB[1]);
        qb.z = 0.25f*(qb.z + hpB[2]); qb.w = 0.25f*(qb.w + hpB[3]);
        const size_t base = (size_t)bc * (size_t)(H >> 1) * W2
                          + (size_t)(r0/2 + i) * W2 + (c0/2 + 4*j);
        *reinterpret_cast<float4*>(o1 + base) = qa;
        *reinterpret_cast<float4*>(o2 + base) = qb;
    }

    const int col = tid & 31;
    const int rg  = tid >> 5;

    float acc[5][4] = {};
    #pragma unroll
    for (int t = 0; t < 14; ++t) {
        const int m = rg * 4 + t;
        #pragma unroll
        for (int s = 0; s < 5; ++s) {
            const float val = varr[s][m][col];
            #pragma unroll
            for (int i = 0; i < 4; ++i) {
                const int tap = t - i;
                if (tap >= 0 && tap <= 10) acc[s][i] += cf.k[tap] * val;
            }
        }
    }

    const float C1 = 1e-4f, C2 = 9e-4f;
    float ssim_acc = 0.f, cs_acc = 0.f;
    #pragma unroll
    for (int i = 0; i < 4; ++i) {
        const float mu1 = acc[0][i], mu2 = acc[1][i];
        const float m11 = acc[2][i], m22 = acc[3][i], m12 = acc[4][i];
        const float mu1s = mu1 * mu1, mu2s = mu2 * mu2, mu12 = mu1 * mu2;
        const float v1 = 2.f * (m12 - mu12) + C2;
        const float v2 = (m11 - mu1s) + (m22 - mu2s) + C2;
        const float r2 = frcp(v2);
        const float rd = frcp(mu1s + mu2s + C1);
        cs_acc   += v1 * r2;
        ssim_acc += (2.f * mu12 + C1) * v1 * r2 * rd;
    }

    #pragma unroll
    for (int off = 32; off > 0; off >>= 1) {
        ssim_acc += __shfl_down(ssim_acc, off);
        cs_acc   += __shfl_down(cs_acc, off);
    }
    const int wave = tid >> 6, lane = tid & 63;
    if (lane == 0) { red[0][wave] = (double)ssim_acc; red[1][wave] = (double)cs_acc; }
    __syncthreads();
    if (tid == 0) {
        double s = red[0][0] + red[0][1] + red[0][2] + red[0][3];
        double c = red[1][0] + red[1][1] + red[1][2] + red[1][3];
        int slot = (blockIdx.x + blockIdx.y * 3 + blockIdx.z * 7) & 63;
        atomicAdd(&accum[slot], s);
        atomicAdd(&accum[64 + slot], c);
    }
}

__global__ __launch_bounds__(64)
void finalize_kernel(const double* __restrict__ accum,  // [5][2][64]
                     float* __restrict__ out, int BC)
{
    __shared__ double sums[5][2];
    int tid = threadIdx.x;
    for (int lvl = 0; lvl < 5; ++lvl) {
        for (int m = 0; m < 2; ++m) {
            double v = accum[(lvl * 2 + m) * 64 + tid];
            for (int off = 32; off > 0; off >>= 1) v += __shfl_down(v, off);
            if (tid == 0) sums[lvl][m] = v;
        }
    }
    __syncthreads();
    if (tid == 0) {
        const double w[5] = {0.0448, 0.2856, 0.3001, 0.2363, 0.1333};
        double prod = 1.0;
        for (int lvl = 0; lvl < 5; ++lvl) {
            int hw = (512 >> lvl);
            double cnt = (double)BC * (double)hw * (double)hw;
            double mssim = sums[lvl][0] / cnt;
            double mcs   = sums[lvl][1] / cnt;
            if (lvl < 4) {
                prod *= pow(mcs, w[lvl]);
            } else {
                double p2 = pow(mssim, w[4]);
                prod *= p2 * p2 * p2 * p2;
            }
        }
        out[0] = (float)(1.0 - prod);
    }
}

extern "C" void kernel_launch(void* const* d_in, const int* in_sizes, int n_in,
                              void* d_out, int out_size, void* d_ws, size_t ws_size,
                              hipStream_t stream) {
    const float* img1 = (const float*)d_in[0];
    const float* img2 = (const float*)d_in[1];
    float* out = (float*)d_out;
    char* ws = (char*)d_ws;

    const int BC = in_sizes[0] / (512 * 512);   // 96

    // ws layout: [0,5120) accum double[5][2][64]; [6144,8192) frag table;
    // pyramid from 8192
    double* accum = (double*)ws;
    uint4*  ftab  = (uint4*)(ws + 6144);
    size_t off = 8192;
    float* lvl1[5] = {nullptr, nullptr, nullptr, nullptr, nullptr};
    float* lvl2[5] = {nullptr, nullptr, nullptr, nullptr, nullptr};
    for (int l = 1; l < 5; ++l) {
        size_t hw = (size_t)(512 >> l) * (512 >> l);
        lvl1[l] = (float*)(ws + off); off += (size_t)BC * hw * sizeof(float);
        lvl2[l] = (float*)(ws + off); off += (size_t)BC * hw * sizeof(float);
    }

    hipMemsetAsync(accum, 0, 5 * 2 * 64 * sizeof(double), stream);

    // Gaussian window, faithful to the reference's POSITIVE exponent bug
    Coeffs cf;
    {
        double kd[11], sum = 0.0;
        for (int i = 0; i < 11; ++i) { kd[i] = exp(((double)((i-5)*(i-5))) / 4.5); sum += kd[i]; }
        for (int i = 0; i < 11; ++i) cf.k[i] = (float)(kd[i] / sum);
    }

    init_frag_kernel<<<1, 64, 0, stream>>>(ftab, cf);

    const float* cur1 = img1;
    const float* cur2 = img2;
    for (int lvl = 0; lvl < 5; ++lvl) {
        int H = 512 >> lvl, W = H;
        float* n1 = (lvl < 4) ? lvl1[lvl + 1] : nullptr;
        float* n2 = (lvl < 4) ? lvl2[lvl + 1] : nullptr;
        if (lvl < 2) {
            dim3 grid(W / 64, H / 32, BC);
            ssim_level_mfma2<<<grid, 256, 0, stream>>>(cur1, cur2, n1, n2, H, W,
                                                       accum + lvl * 128, ftab);
        } else {
            dim3 grid(W / 32, H / 32, BC);
            ssim_level_f32<<<grid, 256, 0, stream>>>(cur1, cur2, n1, n2, H, W,
                                                     accum + lvl * 128, cf);
        }
        cur1 = n1; cur2 = n2;
    }

    finalize_kernel<<<1, 64, 0, stream>>>(accum, out, BC);
}

// Round 17
// 157.775 us; speedup vs baseline: 1.2838x; 1.0023x over previous
//
#include <hip/hip_runtime.h>
#include <cmath>

typedef _Float16 f16x8 __attribute__((ext_vector_type(8)));
typedef float f32x4 __attribute__((ext_vector_type(4)));

struct Coeffs { float k[11]; };

__device__ __forceinline__ unsigned pkh(float lo, float hi) {  // packed f16 pair (RTZ)
    unsigned d;
    asm("v_cvt_pkrtz_f16_f32 %0, %1, %2" : "=v"(d) : "v"(lo), "v"(hi));
    return d;
}

__device__ __forceinline__ unsigned pk_mul(unsigned x, unsigned y) {  // v_pk_mul_f16
    unsigned d;
    asm("v_pk_mul_f16 %0, %1, %2" : "=v"(d) : "v"(x), "v"(y));
    return d;
}

__device__ __forceinline__ float frcp(float x) { return __builtin_amdgcn_rcpf(x); }

__device__ __forceinline__ float4 ld4s(const float* __restrict__ p, int r, int c, int H, int W) {
    float4 v = make_float4(0.f, 0.f, 0.f, 0.f);
    if (r >= 0 && r < H) {
        const float* row = p + (size_t)r * W;
        if (c >= 0 && c + 3 < W) {
            v = *reinterpret_cast<const float4*>(row + c);
        } else {
            if (c + 0 >= 0 && c + 0 < W) v.x = row[c + 0];
            if (c + 1 >= 0 && c + 1 < W) v.y = row[c + 1];
            if (c + 2 >= 0 && c + 2 < W) v.z = row[c + 2];
            if (c + 3 >= 0 && c + 3 < W) v.w = row[c + 3];
        }
    }
    return v;
}

union FragU { ushort us[8]; f16x8 v; uint4 q; };
union RdU   { uint4 q; f16x8 v; };

// ============ init: build banded MFMA fragments once into d_ws =====================
__global__ __launch_bounds__(64)
void init_frag_kernel(uint4* __restrict__ tab, Coeffs cf) {
    const int lane = threadIdx.x;
    const int lj   = lane & 15;
    const int part = lane >> 4;
    FragU bHf, aVf;
    #pragma unroll
    for (int i = 0; i < 8; ++i) {
        const int kk = part * 8 + i;
        const int tH = kk - lj - 3;     // B_H[kk][j] = k[kk-j-3]
        const int tV = kk - lj;         // A_V[j][kk] = k[kk-j]
        float vH = 0.f, vV = 0.f;
        #pragma unroll
        for (int tt = 0; tt < 11; ++tt) {
            vH = (tH == tt) ? cf.k[tt] : vH;
            vV = (tV == tt) ? cf.k[tt] : vV;
        }
        _Float16 hH = (_Float16)vH;
        _Float16 hV = (_Float16)vV;
        bHf.us[i] = __builtin_bit_cast(ushort, hH);
        aVf.us[i] = __builtin_bit_cast(ushort, hV);
    }
    tab[lane]      = bHf.q;
    tab[64 + lane] = aVf.q;
}

// ---------------- MFMA-kernel helpers ----------------------------------------------
__device__ __forceinline__ void stage_load(const float* __restrict__ p1,
                                           const float* __restrict__ p2,
                                           int H, int W, int gr, int gc0,
                                           float (&a)[12], float (&b)[12]) {
    if (gr >= 0 && gr < H && gc0 >= 0 && gc0 + 12 <= W) {
        const size_t idx = (size_t)gr * W + gc0;
        #pragma unroll
        for (int g = 0; g < 3; ++g) {
            float4 va = *reinterpret_cast<const float4*>(p1 + idx + 4 * g);
            float4 vb = *reinterpret_cast<const float4*>(p2 + idx + 4 * g);
            a[4*g+0]=va.x; a[4*g+1]=va.y; a[4*g+2]=va.z; a[4*g+3]=va.w;
            b[4*g+0]=vb.x; b[4*g+1]=vb.y; b[4*g+2]=vb.z; b[4*g+3]=vb.w;
        }
    } else {
        #pragma unroll
        for (int g = 0; g < 3; ++g) {
            float4 va = ld4s(p1, gr, gc0 + 4 * g, H, W);
            float4 vb = ld4s(p2, gr, gc0 + 4 * g, H, W);
            a[4*g+0]=va.x; a[4*g+1]=va.y; a[4*g+2]=va.z; a[4*g+3]=va.w;
            b[4*g+0]=vb.x; b[4*g+1]=vb.y; b[4*g+2]=vb.z; b[4*g+3]=vb.w;
        }
    }
}

__device__ __forceinline__ void stage_write(const float (&a)[12], const float (&b)[12],
                                            char* q0, char* q1, char* q2) {
    unsigned pks[2][6];
    #pragma unroll
    for (int e = 0; e < 6; ++e) {
        pks[0][e] = pkh(a[2*e], a[2*e+1]);
        pks[1][e] = pkh(b[2*e], b[2*e+1]);
    }
    #pragma unroll
    for (int s = 0; s < 2; ++s) {
        *(uint2*)(q0 + s * 6144) = make_uint2(pks[s][0], pks[s][1]);
        *(uint2*)(q1 + s * 6144) = make_uint2(pks[s][2], pks[s][3]);
        *(uint2*)(q2 + s * 6144) = make_uint2(pks[s][4], pks[s][5]);
    }
}

__device__ __forceinline__ void h_phase(const char* a0p, const char* a1p, char* st,
                                        const f16x8 bH, const f32x4 zf) {
    #pragma unroll
    for (int cg = 0; cg < 2; ++cg) {
        const char* ap = cg ? a1p : a0p;
        uint4 da = *(const uint4*)(ap);           // stream a (8 f16)
        uint4 db = *(const uint4*)(ap + 6144);    // stream b
        uint4 qaa, qbb, qab;
        qaa.x = pk_mul(da.x, da.x); qaa.y = pk_mul(da.y, da.y);
        qaa.z = pk_mul(da.z, da.z); qaa.w = pk_mul(da.w, da.w);
        qbb.x = pk_mul(db.x, db.x); qbb.y = pk_mul(db.y, db.y);
        qbb.z = pk_mul(db.z, db.z); qbb.w = pk_mul(db.w, db.w);
        qab.x = pk_mul(da.x, db.x); qab.y = pk_mul(da.y, db.y);
        qab.z = pk_mul(da.z, db.z); qab.w = pk_mul(da.w, db.w);
        RdU f0, f1, f2, f3, f4;
        f0.q = da; f1.q = db; f2.q = qaa; f3.q = qbb; f4.q = qab;
        f32x4 d0 = __builtin_amdgcn_mfma_f32_16x16x32_f16(f0.v, bH, zf, 0, 0, 0);
        f32x4 d1 = __builtin_amdgcn_mfma_f32_16x16x32_f16(f1.v, bH, zf, 0, 0, 0);
        f32x4 d2 = __builtin_amdgcn_mfma_f32_16x16x32_f16(f2.v, bH, zf, 0, 0, 0);
        f32x4 d3 = __builtin_amdgcn_mfma_f32_16x16x32_f16(f3.v, bH, zf, 0, 0, 0);
        f32x4 d4 = __builtin_amdgcn_mfma_f32_16x16x32_f16(f4.v, bH, zf, 0, 0, 0);
        char* sc = st + cg * 2048;
        *(uint2*)(sc)          = make_uint2(pkh(d0[0], d0[1]), pkh(d0[2], d0[3]));
        *(uint2*)(sc + 4096)   = make_uint2(pkh(d1[0], d1[1]), pkh(d1[2], d1[3]));
        *(uint2*)(sc + 8192)   = make_uint2(pkh(d2[0], d2[1]), pkh(d2[2], d2[3]));
        *(uint2*)(sc + 12288)  = make_uint2(pkh(d3[0], d3[1]), pkh(d3[2], d3[3]));
        *(uint2*)(sc + 16384)  = make_uint2(pkh(d4[0], d4[1]), pkh(d4[2], d4[3]));
    }
}

__device__ __forceinline__ void v_phase(const char* hb, const f16x8 aV, const f32x4 zf,
                                        float& ssim_acc, float& cs_acc) {
    f32x4 acc[5];
    #pragma unroll
    for (int s = 0; s < 5; ++s) {
        RdU br;
        br.q = *(const uint4*)(hb + s * 4096);
        acc[s] = __builtin_amdgcn_mfma_f32_16x16x32_f16(aV, br.v, zf, 0, 0, 0);
    }
    const float C1 = 1e-4f, C2 = 9e-4f;
    #pragma unroll
    for (int r = 0; r < 4; ++r) {
        const float mu1 = acc[0][r], mu2 = acc[1][r];
        const float m11 = acc[2][r], m22 = acc[3][r], m12 = acc[4][r];
        const float mu1s = mu1 * mu1, mu2s = mu2 * mu2, mu12 = mu1 * mu2;
        const float v1 = 2.f * (m12 - mu12) + C2;
        const float v2 = (m11 - mu1s) + (m22 - mu2s) + C2;
        const float r2 = frcp(v2);
        const float rd = frcp(mu1s + mu2s + C1);
        cs_acc   += v1 * r2;
        ssim_acc += (2.f * mu12 + C1) * v1 * r2 * rd;
    }
}

__device__ __forceinline__ void pool_load8(const float* __restrict__ p1,
                                           const float* __restrict__ p2,
                                           size_t idx, int W, float4 (&P)[8]) {
    P[0] = *reinterpret_cast<const float4*>(p1 + idx);
    P[1] = *reinterpret_cast<const float4*>(p1 + idx + 4);
    P[2] = *reinterpret_cast<const float4*>(p1 + idx + W);
    P[3] = *reinterpret_cast<const float4*>(p1 + idx + W + 4);
    P[4] = *reinterpret_cast<const float4*>(p2 + idx);
    P[5] = *reinterpret_cast<const float4*>(p2 + idx + 4);
    P[6] = *reinterpret_cast<const float4*>(p2 + idx + W);
    P[7] = *reinterpret_cast<const float4*>(p2 + idx + W + 4);
}

__device__ __forceinline__ void pool_store8(const float4 (&P)[8],
                                            float* __restrict__ o1, float* __restrict__ o2,
                                            int bc, int H, int W, int r0, int c0t,
                                            int i, int h) {
    float4 oa, ob;
    oa.x = 0.25f*(P[0].x+P[0].y+P[2].x+P[2].y); oa.y = 0.25f*(P[0].z+P[0].w+P[2].z+P[2].w);
    oa.z = 0.25f*(P[1].x+P[1].y+P[3].x+P[3].y); oa.w = 0.25f*(P[1].z+P[1].w+P[3].z+P[3].w);
    ob.x = 0.25f*(P[4].x+P[4].y+P[6].x+P[6].y); ob.y = 0.25f*(P[4].z+P[4].w+P[6].z+P[6].w);
    ob.z = 0.25f*(P[5].x+P[5].y+P[7].x+P[7].y); ob.w = 0.25f*(P[5].z+P[5].w+P[7].z+P[7].w);
    const int W2 = W >> 1;
    const size_t base = (size_t)bc * (size_t)(H >> 1) * W2
                      + (size_t)(r0/2 + i) * W2 + (c0t/2 + 4*h);
    *reinterpret_cast<float4*>(o1 + base) = oa;
    *reinterpret_cast<float4*>(o2 + base) = ob;
}

// ============ Levels 0-1: 2-tile pipelined, 2-stream A_lds MFMA kernel =============
// grid (W/64, H/32, B*C). Block handles tiles (c0, c0+32) with prefetched registers.
__global__ __launch_bounds__(256)
void ssim_level_mfma2(const float* __restrict__ i1, const float* __restrict__ i2,
                      float* __restrict__ o1, float* __restrict__ o2,
                      int H, int W,
                      double* __restrict__ accum,
                      const uint4* __restrict__ frag_tab)
{
    __shared__ __align__(16) ushort A_lds[2][48][64];   // 12.3 KB (a,b only)
    __shared__ __align__(16) ushort H_T [5][32][64];    // 20.5 KB
    __shared__ double red[2][4];

    const int tid  = threadIdx.x;
    const int lane = tid & 63;
    const int lj   = lane & 15;
    const int part = lane >> 4;
    const int swz  = (lane & 7) << 4;
    const int wv   = __builtin_amdgcn_readfirstlane(tid) >> 6;

    const int bc = blockIdx.z;
    const int r0 = blockIdx.y * 32;
    const int c0 = blockIdx.x * 64;
    const float* p1 = i1 + (size_t)bc * H * W;
    const float* p2 = i2 + (size_t)bc * H * W;

    RdU bHu, aVu;
    bHu.q = frag_tab[lane];
    aVu.q = frag_tab[64 + lane];
    const f16x8 bH = bHu.v;
    const f16x8 aV = aVu.v;
    const f32x4 zf = {0.f, 0.f, 0.f, 0.f};

    float ssim_acc = 0.f, cs_acc = 0.f;

    // ---- Step 1: issue ALL global loads (both tiles); write tile A to A_lds ----
    float aB[12], bB[12];                 // tile-B stage, carried across tile A
    char *q0 = nullptr, *q1 = nullptr, *q2 = nullptr;
    if (tid < 192) {
        const int row_rel = tid >> 2;     // 0..47
        const int colg    = tid & 3;
        const int gr  = r0 - 5 + row_rel;
        const int gcA = c0 - 8 + 12 * colg;
        float aA[12], bA[12];
        stage_load(p1, p2, H, W, gr, gcA,      aA, bA);
        stage_load(p1, p2, H, W, gr, gcA + 32, aB, bB);
        const int cb   = 24 * colg;
        const int swzr = (row_rel & 7) << 4;
        char* base0 = (char*)&A_lds[0][0][0] + row_rel * 128;
        q0 = base0 + ((cb)      ^ swzr);
        q1 = base0 + ((cb + 8)  ^ swzr);
        q2 = base0 + ((cb + 16) ^ swzr);
        stage_write(aA, bA, q0, q1, q2);
    } else if (o1 != nullptr) {
        // pool wave: load + pool + store both tiles (f32-exact)
        const int p = tid - 192;
        const int i = p & 15;
        const int h = p >> 4;
        const size_t idxA = (size_t)(r0 + 2 * i) * W + (c0 + 8 * h);
        float4 PA[8], PB[8];
        pool_load8(p1, p2, idxA,      W, PA);
        pool_load8(p1, p2, idxA + 32, W, PB);
        pool_store8(PA, o1, o2, bc, H, W, r0, c0,      i, h);
        pool_store8(PB, o1, o2, bc, H, W, r0, c0 + 32, i, h);
    }
    __syncthreads();

    // loop-invariant phase addresses
    const char* Ab  = (const char*)&A_lds[0][0][0] + wv * 2048 + lj * 128;
    const char* a0p = Ab + ((part * 16)      ^ swz);
    const char* a1p = Ab + ((32 + part * 16) ^ swz);
    char* st = (char*)&H_T[0][0][0] + lj * 128 + ((wv * 32 + part * 8) ^ swz);
    const int rg2 = wv >> 1, cg2 = wv & 1;
    const char* hb = (const char*)&H_T[0][0][0] + cg2 * 2048 + lj * 128
                   + ((rg2 * 32 + part * 16) ^ swz);

    // ---- Step 2: H(A) ----
    if (wv < 3) h_phase(a0p, a1p, st, bH, zf);
    __syncthreads();

    // ---- Step 3: V(A)+SSIM; stagers drop prefetched tile B into A_lds ----
    if (tid < 192) stage_write(aB, bB, q0, q1, q2);
    v_phase(hb, aV, zf, ssim_acc, cs_acc);
    __syncthreads();

    // ---- Step 4: H(B) ----
    if (wv < 3) h_phase(a0p, a1p, st, bH, zf);
    __syncthreads();

    // ---- Step 5: V(B)+SSIM ----
    v_phase(hb, aV, zf, ssim_acc, cs_acc);

    // ---- single reduction + atomic for both tiles ----
    #pragma unroll
    for (int off = 32; off > 0; off >>= 1) {
        ssim_acc += __shfl_down(ssim_acc, off);
        cs_acc   += __shfl_down(cs_acc, off);
    }
    if (lane == 0) { red[0][wv] = (double)ssim_acc; red[1][wv] = (double)cs_acc; }
    __syncthreads();
    if (tid == 0) {
        double s = red[0][0] + red[0][1] + red[0][2] + red[0][3];
        double c = red[1][0] + red[1][1] + red[1][2] + red[1][3];
        int slot = (blockIdx.x + blockIdx.y * 3 + blockIdx.z * 7) & 63;
        atomicAdd(&accum[slot], s);
        atomicAdd(&accum[64 + slot], c);
    }
}

// =================== f32 kernel (proven): levels 2-4 ===============================
#define SPF 33
#define HRF 42

__global__ __launch_bounds__(256)
void ssim_level_f32(const float* __restrict__ i1, const float* __restrict__ i2,
                    float* __restrict__ o1, float* __restrict__ o2,
                    int H, int W,
                    double* __restrict__ accum, Coeffs cf)
{
    __shared__ __align__(16) float varr[5][HRF][SPF];
    __shared__ __align__(16) float phl[2][16][16];
    __shared__ double red[2][4];

    const int tid = threadIdx.x;
    const int bc  = blockIdx.z;
    const int r0 = blockIdx.y * 32;
    const int c0 = blockIdx.x * 32;
    const float* p1 = i1 + (size_t)bc * H * W;
    const float* p2 = i2 + (size_t)bc * H * W;

    const int row_rel = tid >> 2;
    const int j  = tid & 3;
    const int cl = 8 * j;
    float hpA[4], hpB[4];
    bool pool_thread = false;

    if (tid < HRF * 4) {
        const int gr  = r0 + row_rel - 5;
        const int gcb = c0 + cl - 8;

        float a[24], b[24];
        if (gr >= 0 && gr < H && gcb >= 0 && gcb + 24 <= W) {
            const size_t idx = (size_t)gr * W + gcb;
            const float* pa = p1 + idx;
            const float* pb = p2 + idx;
            #pragma unroll
            for (int g = 0; g < 6; ++g) {
                float4 va = *reinterpret_cast<const float4*>(pa + 4 * g);
                float4 vb = *reinterpret_cast<const float4*>(pb + 4 * g);
                a[4*g+0]=va.x; a[4*g+1]=va.y; a[4*g+2]=va.z; a[4*g+3]=va.w;
                b[4*g+0]=vb.x; b[4*g+1]=vb.y; b[4*g+2]=vb.z; b[4*g+3]=vb.w;
            }
        } else {
            #pragma unroll
            for (int g = 0; g < 6; ++g) {
                float4 va = ld4s(p1, gr, gcb + 4 * g, H, W);
                float4 vb = ld4s(p2, gr, gcb + 4 * g, H, W);
                a[4*g+0]=va.x; a[4*g+1]=va.y; a[4*g+2]=va.z; a[4*g+3]=va.w;
                b[4*g+0]=vb.x; b[4*g+1]=vb.y; b[4*g+2]=vb.z; b[4*g+3]=vb.w;
            }
        }

        float acc[5][8] = {};
        #pragma unroll
        for (int i = 0; i < 24; ++i) {
            float av = a[i], bv = b[i];
            float pa2 = av * av, pb2 = bv * bv, pab = av * bv;
            #pragma unroll
            for (int jo = 0; jo < 8; ++jo) {
                const int t = i - 3 - jo;
                if (t >= 0 && t <= 10) {
                    const float kk = cf.k[t];
                    acc[0][jo] += kk * av;  acc[1][jo] += kk * bv;
                    acc[2][jo] += kk * pa2; acc[3][jo] += kk * pb2;
                    acc[4][jo] += kk * pab;
                }
            }
        }
        #pragma unroll
        for (int s = 0; s < 5; ++s) {
            *reinterpret_cast<float4*>(&varr[s][row_rel][cl]) =
                make_float4(acc[s][0], acc[s][1], acc[s][2], acc[s][3]);
            *reinterpret_cast<float4*>(&varr[s][row_rel][cl + 4]) =
                make_float4(acc[s][4], acc[s][5], acc[s][6], acc[s][7]);
        }

        if (o1 != nullptr && row_rel >= 5 && row_rel <= 36) {
            #pragma unroll
            for (int p = 0; p < 4; ++p) {
                hpA[p] = a[8 + 2*p] + a[9 + 2*p];
                hpB[p] = b[8 + 2*p] + b[9 + 2*p];
            }
            if (row_rel & 1) {
                const int i = (row_rel - 5) >> 1;
                *reinterpret_cast<float4*>(&phl[0][i][4*j]) = make_float4(hpA[0],hpA[1],hpA[2],hpA[3]);
                *reinterpret_cast<float4*>(&phl[1][i][4*j]) = make_float4(hpB[0],hpB[1],hpB[2],hpB[3]);
            } else if (row_rel >= 6) {
                pool_thread = true;
            }
        }
    }
    __syncthreads();

    if (pool_thread) {
        const int i = (row_rel - 6) >> 1;
        const int W2 = W >> 1;
        float4 qa = *reinterpret_cast<const float4*>(&phl[0][i][4*j]);
        float4 qb = *reinterpret_cast<const float4*>(&phl[1][i][4*j]);
        qa.x = 0.25f*(qa.x + hpA[0]); qa.y = 0.25f*(qa.y + hpA[1]);
        qa.z = 0.25f*(qa.z + hpA[2]); qa.w = 0.25f*(qa.w + hpA[3]);
        qb.x = 0.25f*(qb.x + hpB[0]); qb.y = 0.25f*(qb.y + hpB[1]);
        qb.z = 0.25f*(qb.z + hpB[2]); qb.w = 0.25f*(qb.w + hpB[3]);
        const size_t base = (size_t)bc * (size_t)(H >> 1) * W2
                          + (size_t)(r0/2 + i) * W2 + (c0/2 + 4*j);
        *reinterpret_cast<float4*>(o1 + base) = qa;
        *reinterpret_cast<float4*>(o2 + base) = qb;
    }

    const int col = tid & 31;
    const int rg  = tid >> 5;

    float acc[5][4] = {};
    #pragma unroll
    for (int t = 0; t < 14; ++t) {
        const int m = rg * 4 + t;
        #pragma unroll
        for (int s = 0; s < 5; ++s) {
            const float val = varr[s][m][col];
            #pragma unroll
            for (int i = 0; i < 4; ++i) {
                const int tap = t - i;
                if (tap >= 0 && tap <= 10) acc[s][i] += cf.k[tap] * val;
            }
        }
    }

    const float C1 = 1e-4f, C2 = 9e-4f;
    float ssim_acc = 0.f, cs_acc = 0.f;
    #pragma unroll
    for (int i = 0; i < 4; ++i) {
        const float mu1 = acc[0][i], mu2 = acc[1][i];
        const float m11 = acc[2][i], m22 = acc[3][i], m12 = acc[4][i];
        const float mu1s = mu1 * mu1, mu2s = mu2 * mu2, mu12 = mu1 * mu2;
        const float v1 = 2.f * (m12 - mu12) + C2;
        const float v2 = (m11 - mu1s) + (m22 - mu2s) + C2;
        const float r2 = frcp(v2);
        const float rd = frcp(mu1s + mu2s + C1);
        cs_acc   += v1 * r2;
        ssim_acc += (2.f * mu12 + C1) * v1 * r2 * rd;
    }

    #pragma unroll
    for (int off = 32; off > 0; off >>= 1) {
        ssim_acc += __shfl_down(ssim_acc, off);
        cs_acc   += __shfl_down(cs_acc, off);
    }
    const int wave = tid >> 6, lane = tid & 63;
    if (lane == 0) { red[0][wave] = (double)ssim_acc; red[1][wave] = (double)cs_acc; }
    __syncthreads();
    if (tid == 0) {
        double s = red[0][0] + red[0][1] + red[0][2] + red[0][3];
        double c = red[1][0] + red[1][1] + red[1][2] + red[1][3];
        int slot = (blockIdx.x + blockIdx.y * 3 + blockIdx.z * 7) & 63;
        atomicAdd(&accum[slot], s);
        atomicAdd(&accum[64 + slot], c);
    }
}

__global__ __launch_bounds__(64)
void finalize_kernel(const double* __restrict__ accum,  // [5][2][64]
                     float* __restrict__ out, int BC)
{
    __shared__ double sums[5][2];
    int tid = threadIdx.x;
    for (int lvl = 0; lvl < 5; ++lvl) {
        for (int m = 0; m < 2; ++m) {
            double v = accum[(lvl * 2 + m) * 64 + tid];
            for (int off = 32; off > 0; off >>= 1) v += __shfl_down(v, off);
            if (tid == 0) sums[lvl][m] = v;
        }
    }
    __syncthreads();
    if (tid == 0) {
        const double w[5] = {0.0448, 0.2856, 0.3001, 0.2363, 0.1333};
        double prod = 1.0;
        for (int lvl = 0; lvl < 5; ++lvl) {
            int hw = (512 >> lvl);
            double cnt = (double)BC * (double)hw * (double)hw;
            double mssim = sums[lvl][0] / cnt;
            double mcs   = sums[lvl][1] / cnt;
            if (lvl < 4) {
                prod *= pow(mcs, w[lvl]);
            } else {
                double p2 = pow(mssim, w[4]);
                prod *= p2 * p2 * p2 * p2;
            }
        }
        out[0] = (float)(1.0 - prod);
    }
}

extern "C" void kernel_launch(void* const* d_in, const int* in_sizes, int n_in,
                              void* d_out, int out_size, void* d_ws, size_t ws_size,
                              hipStream_t stream) {
    const float* img1 = (const float*)d_in[0];
    const float* img2 = (const float*)d_in[1];
    float* out = (float*)d_out;
    char* ws = (char*)d_ws;

    const int BC = in_sizes[0] / (512 * 512);   // 96

    // ws layout: [0,5120) accum double[5][2][64]; [6144,8192) frag table;
    // pyramid from 8192
    double* accum = (double*)ws;
    uint4*  ftab  = (uint4*)(ws + 6144);
    size_t off = 8192;
    float* lvl1[5] = {nullptr, nullptr, nullptr, nullptr, nullptr};
    float* lvl2[5] = {nullptr, nullptr, nullptr, nullptr, nullptr};
    for (int l = 1; l < 5; ++l) {
        size_t hw = (size_t)(512 >> l) * (512 >> l);
        lvl1[l] = (float*)(ws + off); off += (size_t)BC * hw * sizeof(float);
        lvl2[l] = (float*)(ws + off); off += (size_t)BC * hw * sizeof(float);
    }

    (void)hipMemsetAsync(accum, 0, 5 * 2 * 64 * sizeof(double), stream);

    // Gaussian window, faithful to the reference's POSITIVE exponent bug
    Coeffs cf;
    {
        double kd[11], sum = 0.0;
        for (int i = 0; i < 11; ++i) { kd[i] = exp(((double)((i-5)*(i-5))) / 4.5); sum += kd[i]; }
        for (int i = 0; i < 11; ++i) cf.k[i] = (float)(kd[i] / sum);
    }

    init_frag_kernel<<<1, 64, 0, stream>>>(ftab, cf);

    const float* cur1 = img1;
    const float* cur2 = img2;
    for (int lvl = 0; lvl < 5; ++lvl) {
        int H = 512 >> lvl, W = H;
        float* n1 = (lvl < 4) ? lvl1[lvl + 1] : nullptr;
        float* n2 = (lvl < 4) ? lvl2[lvl + 1] : nullptr;
        if (lvl < 2) {
            dim3 grid(W / 64, H / 32, BC);
            ssim_level_mfma2<<<grid, 256, 0, stream>>>(cur1, cur2, n1, n2, H, W,
                                                       accum + lvl * 128, ftab);
        } else {
            dim3 grid(W / 32, H / 32, BC);
            ssim_level_f32<<<grid, 256, 0, stream>>>(cur1, cur2, n1, n2, H, W,
                                                     accum + lvl * 128, cf);
        }
        cur1 = n1; cur2 = n2;
    }

    finalize_kernel<<<1, 64, 0, stream>>>(accum, out, BC);
}